// Round 7
// baseline (604.828 us; speedup 1.0000x reference)
//
#include <hip/hip_runtime.h>
#include <stdint.h>

#define N_TOK 16384
#define DDIM  1024
#define HDIM  4096
#define NEXP  8
#define BM    256
#define MAXMT 72
#define MAXNR 5

typedef __attribute__((ext_vector_type(8))) short short8;
typedef __attribute__((ext_vector_type(4))) float f32x4;

__device__ __forceinline__ unsigned short f2b(float f) {
    union { float f; unsigned int u; } x; x.f = f;
    unsigned int r = x.u + 0x7FFFu + ((x.u >> 16) & 1u);
    return (unsigned short)(r >> 16);
}

// K1: router (fp64 accumulate => argmax matches numpy) + x -> bf16 cast.
__global__ __launch_bounds__(256)
void k_router_cast(const float* __restrict__ x, const float* __restrict__ Wr,
                   const float* __restrict__ br, unsigned short* __restrict__ xb,
                   int* __restrict__ eid)
{
    __shared__ float wr[NEXP * DDIM];
    const int t = threadIdx.x;
    for (int i = t; i < NEXP * DDIM / 4; i += 256)
        ((float4*)wr)[i] = ((const float4*)Wr)[i];
    __syncthreads();
    const int lane = t & 63;
    const int n = blockIdx.x * 4 + (t >> 6);
    const float* xr = x + (size_t)n * DDIM;
    double acc[NEXP];
#pragma unroll
    for (int e = 0; e < NEXP; ++e) acc[e] = 0.0;
#pragma unroll
    for (int j = 0; j < 4; ++j) {
        const int d = j * 256 + lane * 4;
        float4 v = *(const float4*)(xr + d);
        unsigned long long pk =
            (unsigned long long)(f2b(v.x) | ((unsigned int)f2b(v.y) << 16)) |
            ((unsigned long long)(f2b(v.z) | ((unsigned int)f2b(v.w) << 16)) << 32);
        *(unsigned long long*)(xb + (size_t)n * DDIM + d) = pk;
#pragma unroll
        for (int e = 0; e < NEXP; ++e) {
            const float* w = wr + e * DDIM + d;
            acc[e] += (double)v.x * (double)w[0];
            acc[e] += (double)v.y * (double)w[1];
            acc[e] += (double)v.z * (double)w[2];
            acc[e] += (double)v.w * (double)w[3];
        }
    }
#pragma unroll
    for (int e = 0; e < NEXP; ++e)
#pragma unroll
        for (int off = 32; off > 0; off >>= 1)
            acc[e] += __shfl_down(acc[e], off);
    if (lane == 0) {
        double best = acc[0] + (double)br[0];
        int bi = 0;
#pragma unroll
        for (int e = 1; e < NEXP; ++e) {
            double v = acc[e] + (double)br[e];
            if (v > best) { best = v; bi = e; }
        }
        eid[n] = bi;
    }
}

// K2: histogram — LDS counts then <=8 padded (64B-stride) global atomics/block.
__global__ __launch_bounds__(256)
void k_hist(const int* __restrict__ eid, int* __restrict__ counts)
{
    __shared__ int h[NEXP];
    const int t = threadIdx.x;
    if (t < NEXP) h[t] = 0;
    __syncthreads();
    atomicAdd(&h[eid[blockIdx.x * 256 + t]], 1);
    __syncthreads();
    if (t < NEXP && h[t]) atomicAdd(&counts[t * 16], h[t]);
}

// K3: tile table + realM
__global__ void k_scan(const int* __restrict__ counts, int* __restrict__ texp,
                       int* __restrict__ pbase)
{
    if (threadIdx.x == 0) {
        int tt = 0;
        for (int e = 0; e < NEXP; ++e) {
            pbase[e] = tt * BM;
            const int nt = (counts[e * 16] + BM - 1) / BM;
            for (int i = 0; i < nt; ++i) texp[tt++] = e;
        }
        pbase[8] = tt;                       // realM (<= 71)
        for (; tt < MAXMT; ++tt) texp[tt] = -1;
    }
}

// K4: scatter — LDS rank + one padded global atomic per (block, expert).
__global__ __launch_bounds__(256)
void k_scatter(const int* __restrict__ eid, const int* __restrict__ pbase,
               int* __restrict__ cursors, int* __restrict__ perm)
{
    __shared__ int h[NEXP];
    __shared__ int base[NEXP];
    const int t = threadIdx.x;
    if (t < NEXP) h[t] = 0;
    __syncthreads();
    const int n = blockIdx.x * 256 + t;
    const int e = eid[n];
    const int rank = atomicAdd(&h[e], 1);
    __syncthreads();
    if (t < NEXP) base[t] = h[t] ? atomicAdd(&cursors[t * 16], h[t]) : 0;
    __syncthreads();
    perm[pbase[e] + base[e] + rank] = n;
}

// K5a: W_comb[e] = bf16(Ws + We[e])
__global__ __launch_bounds__(256)
void k_combine_w(const float* __restrict__ Ws, const float* __restrict__ We,
                 unsigned short* __restrict__ wc)
{
    const size_t i = ((size_t)blockIdx.x * 256 + threadIdx.x) * 8;
    const size_t hd = i & (size_t)(HDIM * DDIM - 1);
    float4 a0 = *(const float4*)(We + i);
    float4 a1 = *(const float4*)(We + i + 4);
    float4 b0 = *(const float4*)(Ws + hd);
    float4 b1 = *(const float4*)(Ws + hd + 4);
    uint4 o;
    o.x = f2b(a0.x + b0.x) | ((unsigned)f2b(a0.y + b0.y) << 16);
    o.y = f2b(a0.z + b0.z) | ((unsigned)f2b(a0.w + b0.w) << 16);
    o.z = f2b(a1.x + b1.x) | ((unsigned)f2b(a1.y + b1.y) << 16);
    o.w = f2b(a1.z + b1.z) | ((unsigned)f2b(a1.w + b1.w) << 16);
    *(uint4*)(wc + i) = o;
}

// K5b: b_comb[e] = bs + be[e]
__global__ __launch_bounds__(256)
void k_combine_b(const float* __restrict__ bs, const float* __restrict__ be,
                 float* __restrict__ bc)
{
    const int i = blockIdx.x * 256 + threadIdx.x;
    bc[i] = bs[i & (HDIM - 1)] + be[i];
}

// K6: PERSISTENT gathered GEMM (template).
// MODE 0: real kernel (round-6 schedule, unchanged).
// MODE 1: DIAGNOSTIC — identical skeleton + ds_reads + MFMA, but all
//         global_load_lds suppressed (vm waits instant) and stores
//         predicated off (impossible token) so acc stays live (no DCE).
//         REP repeats the whole tile loop to make the dispatch visible
//         in the top-k profile. Output is never written by MODE 1.
#define SBAR()   __builtin_amdgcn_s_barrier()
#define SCHED0() __builtin_amdgcn_sched_barrier(0)
#define LGKM0()  asm volatile("s_waitcnt lgkmcnt(0)" ::: "memory")

template<int MODE, int REP>
__global__ __launch_bounds__(512, 2)
void k_gemm_t(const unsigned short* __restrict__ X, const unsigned short* __restrict__ W,
              const float* __restrict__ bc, const int* __restrict__ perm,
              const int* __restrict__ texp, const int* __restrict__ realM_p,
              float* __restrict__ out)
{
    __shared__ unsigned short lds[65536];       // 128 KiB ring
    __shared__ int   toksLDS[MAXNR][256];       // epilogue scatter targets
    __shared__ float biasLDS[MAXNR][256];       // per-wg bias row (block's 256 cols)

    const int realM = realM_p[8];
    const int base  = blockIdx.x;
    const int tnr   = base & 15;
    const int tmB   = base >> 4;
    const int nR    = (realM - tmB + 15) >> 4;  // 4..5
    const int T     = nR << 4;

    const int t    = threadIdx.x;
    const int lane = t & 63;
    const int wid  = t >> 6;
    const int wm   = wid >> 2;
    const int wn   = wid & 3;

    const int srow    = t >> 3;                        // 0..63
    const int schunkE = (((t & 7) ^ (srow & 7)) << 3); // swizzled src k-offset
    unsigned short* dstT = lds + (t << 3);

    const int rA   = lane & 15;
    const int c0   = ((lane >> 4) << 3) ^ ((lane & 7) << 3);
    const int c1   = c0 ^ 32;
    const int aBase = ((2 + wm) << 13) + (rA << 6);
    const int bBase = ((wn >> 1) << 13) + ((wn & 1) << 12) + (rA << 6);
    const int colBase = tnr * 256 + wn * 64 + rA;

    // ---- upfront metadata (ordinary loads; ring not yet started) ----
    int ePk = 0;
#pragma unroll
    for (int w = 0; w < MAXNR; ++w) {
        const int ev = (w < nR) ? texp[tmB + (w << 4)] : 0;
        ePk |= (ev & 15) << (w << 2);
    }
    if (t < 256) {
#pragma unroll
        for (int w = 0; w < MAXNR; ++w) {
            if (w < nR) {
                toksLDS[w][t] = perm[(tmB + (w << 4)) * 256 + t];
                const int ev = (ePk >> (w << 2)) & 15;
                biasLDS[w][t] = bc[ev * HDIM + tnr * 256 + t];
            }
        }
    }
    __syncthreads();

    f32x4 acc[8][4];
    short8 fa[8][2], fb[4][2];
    int tokCur[4], tokNext[4];

    // staging: sg -> (tile tloc, half h). B halves h=0,1 from W; A h=2,3 from xb.
    auto STAGE = [&](int sg, int tau) {
        if constexpr (MODE == 1) { (void)sg; (void)tau; return; }
        if (sg >= (nR << 6)) return;
        const int tloc = sg >> 2;
        const int h    = sg & 3;
        const int kb   = (tloc & 15) << 6;
        unsigned short* d = dstT + ((tloc & 1) << 15) + (h << 13);
        const unsigned short *s0, *s1;
        if (h < 2) {
            const int wS = tloc >> 4;
            const int ee = (ePk >> (wS << 2)) & 15;
            const size_t r0 = (size_t)(ee * HDIM + tnr * 256 + h * 128 + srow) * DDIM
                              + schunkE + kb;
            s0 = W + r0; s1 = W + r0 + (size_t)64 * DDIM;
        } else {
            const bool nxt = (tloc >> 4) != (tau >> 4);
            const int i0 = (h - 2) << 1;
            const int ta = nxt ? tokNext[i0]     : tokCur[i0];
            const int tb = nxt ? tokNext[i0 + 1] : tokCur[i0 + 1];
            s0 = X + (size_t)ta * DDIM + schunkE + kb;
            s1 = X + (size_t)tb * DDIM + schunkE + kb;
        }
        __builtin_amdgcn_global_load_lds(
            (const __attribute__((address_space(1))) void*)s0,
            (__attribute__((address_space(3))) void*)d, 16, 0, 0);
        __builtin_amdgcn_global_load_lds(
            (const __attribute__((address_space(1))) void*)s1,
            (__attribute__((address_space(3))) void*)(d + 4096), 16, 0, 0);
    };

#define LDA(m) \
    fa[m][0] = *(const short8*)&lds[bufOff + aBase + (m)*1024 + c0]; \
    fa[m][1] = *(const short8*)&lds[bufOff + aBase + (m)*1024 + c1];
#define LDB(n) \
    fb[n][0] = *(const short8*)&lds[bufOff + bBase + (n)*1024 + c0]; \
    fb[n][1] = *(const short8*)&lds[bufOff + bBase + (n)*1024 + c1];
#define MM(m,n) \
    acc[m][n] = __builtin_amdgcn_mfma_f32_16x16x32_bf16(fa[m][0], fb[n][0], acc[m][n], 0,0,0); \
    acc[m][n] = __builtin_amdgcn_mfma_f32_16x16x32_bf16(fa[m][1], fb[n][1], acc[m][n], 0,0,0);

    // ring prologue: tile0 fully landed; 3 half-tiles (6 loads) stay in flight
    {
        // tokCur must be valid before prologue staging
#pragma unroll
        for (int i = 0; i < 4; ++i) {
            int a = toksLDS[0][i * 64 + srow];
            tokCur[i] = a < 0 ? 0 : a;
            int b = (nR > 1) ? toksLDS[1][i * 64 + srow] : 0;
            tokNext[i] = b < 0 ? 0 : b;
        }
    }
#pragma unroll
    for (int s = 0; s < 7; ++s) STAGE(s, 0);
    asm volatile("s_waitcnt vmcnt(6)" ::: "memory");
    SCHED0(); SBAR(); SCHED0();

#pragma unroll 1
    for (int rep = 0; rep < REP; ++rep) {
        int w = 0;
        // (re)init per-sweep state
#pragma unroll
        for (int i = 0; i < 4; ++i) {
            int a = toksLDS[0][i * 64 + srow];
            tokCur[i] = a < 0 ? 0 : a;
            int b = (nR > 1) ? toksLDS[1][i * 64 + srow] : 0;
            tokNext[i] = b < 0 ? 0 : b;
        }
        {
            float bn[4];
#pragma unroll
            for (int n = 0; n < 4; ++n) bn[n] = biasLDS[0][wn * 64 + n * 16 + rA];
#pragma unroll
            for (int m = 0; m < 8; ++m)
#pragma unroll
                for (int n = 0; n < 4; ++n)
                    acc[m][n] = (f32x4){bn[n], bn[n], bn[n], bn[n]};
        }

#pragma unroll 1
        for (int tau = 0; tau < T; ++tau) {
            const int tt = tau & 15;
            const int bufOff = (tau & 1) << 15;
            const int sig = (tau << 2) + 7;

            // ---- tile top: all fragment reads, FIFO-grouped ----
            LDB(0) LDB(1) LDB(2) LDB(3) LDA(0) LDA(1)    // G1: 12 reads
            SCHED0();
            LDA(2) LDA(3)                                // G2: 4 reads
            SCHED0();
            LDA(4) LDA(5) LDA(6) LDA(7)                  // G3: 8 reads
            STAGE(sig, tau);                             // other-buffer H3: always safe
            SCHED0();
            asm volatile("s_waitcnt lgkmcnt(12)" ::: "memory"); SCHED0();
            __builtin_amdgcn_s_setprio(1);
            MM(0,0) MM(0,1) MM(0,2) MM(0,3) MM(1,0) MM(1,1) MM(1,2) MM(1,3)
            __builtin_amdgcn_s_setprio(0); SCHED0();
            asm volatile("s_waitcnt lgkmcnt(8)" ::: "memory"); SCHED0();
            __builtin_amdgcn_s_setprio(1);
            MM(2,0) MM(2,1) MM(2,2) MM(2,3) MM(3,0) MM(3,1) MM(3,2) MM(3,3)
            __builtin_amdgcn_s_setprio(0); SCHED0();
            // ---- mid barrier: all waves' reads complete -> safe to overwrite-stage
            LGKM0(); SBAR(); SCHED0();
            STAGE(sig + 1, tau); STAGE(sig + 2, tau); STAGE(sig + 3, tau);
            SCHED0();
            __builtin_amdgcn_s_setprio(1);
            MM(4,0) MM(4,1) MM(4,2) MM(4,3) MM(5,0) MM(5,1) MM(5,2) MM(5,3)
            MM(6,0) MM(6,1) MM(6,2) MM(6,3) MM(7,0) MM(7,1) MM(7,2) MM(7,3)
            __builtin_amdgcn_s_setprio(0); SCHED0();
            // ---- boundary: tile tau+1 fully landed, 3 stages in flight ----
            if (tau < T - 2)       { asm volatile("s_waitcnt vmcnt(6)" ::: "memory"); }
            else if (tau == T - 2) { asm volatile("s_waitcnt vmcnt(0)" ::: "memory"); }
            SBAR(); SCHED0();

            if (tt == 15) {
                // ---- epilogue for wg w ----
                const int rsub = (lane >> 4) * 4;
#pragma unroll
                for (int m = 0; m < 8; ++m) {
                    const int rl = wm * 128 + m * 16 + rsub;
                    int tk[4];
#pragma unroll
                    for (int j = 0; j < 4; ++j) tk[j] = toksLDS[w][rl + j];
#pragma unroll
                    for (int n = 0; n < 4; ++n) {
                        const int col = colBase + n * 16;
#pragma unroll
                        for (int j = 0; j < 4; ++j) {
                            const bool doSt = (MODE == 0) ? (tk[j] >= 0)
                                                          : (tk[j] == -123456789);
                            if (doSt) out[(size_t)tk[j] * HDIM + col] = acc[m][n][j];
                        }
                    }
                }
                if (w + 1 < nR) {
                    float bn[4];
#pragma unroll
                    for (int n = 0; n < 4; ++n) bn[n] = biasLDS[w + 1][wn * 64 + n * 16 + rA];
#pragma unroll
                    for (int m = 0; m < 8; ++m)
#pragma unroll
                        for (int n = 0; n < 4; ++n)
                            acc[m][n] = (f32x4){bn[n], bn[n], bn[n], bn[n]};
#pragma unroll
                    for (int i = 0; i < 4; ++i) tokCur[i] = tokNext[i];
                    if (w + 2 < nR) {
#pragma unroll
                        for (int i = 0; i < 4; ++i) {
                            int v = toksLDS[w + 2][i * 64 + srow];
                            tokNext[i] = v < 0 ? 0 : v;
                        }
                    }
                }
                ++w;
            }
        }
    }
#undef LDA
#undef LDB
#undef MM
}

extern "C" void kernel_launch(void* const* d_in, const int* in_sizes, int n_in,
                              void* d_out, int out_size, void* d_ws, size_t ws_size,
                              hipStream_t stream)
{
    const float* x  = (const float*)d_in[0];
    const float* Ws = (const float*)d_in[1];
    const float* bs = (const float*)d_in[2];
    const float* We = (const float*)d_in[3];
    const float* be = (const float*)d_in[4];
    const float* Wr = (const float*)d_in[5];
    const float* br = (const float*)d_in[6];
    float* out = (float*)d_out;
    char* ws = (char*)d_ws;

    // workspace layout (~100.94 MB)
    unsigned short* xb  = (unsigned short*)(ws + 0);          // 33,554,432 B
    unsigned short* wc  = (unsigned short*)(ws + 33554432);   // 67,108,864 B
    float*          bc  = (float*)(ws + 100663296);           //    131,072 B
    int*            eid = (int*)(ws + 100794368);             //     65,536 B
    int*            perm= (int*)(ws + 100859904);             //     73,728 B
    int*            cnt = (int*)(ws + 100933632);             // 512 B (padded)
    int*            cur = (int*)(ws + 100934144);             // 512 B (padded)
    int*            pb  = (int*)(ws + 100934656);             // 64 B (pbase + realM@[8])
    int*            texp= (int*)(ws + 100934720);             // 288 B

    hipMemsetAsync(perm, 0xFF, MAXMT * BM * sizeof(int), stream);
    hipMemsetAsync(cnt, 0, 1024, stream);   // cnt + cur

    k_router_cast<<<N_TOK / 4, 256, 0, stream>>>(x, Wr, br, xb, eid);
    k_combine_w<<<(NEXP * (size_t)HDIM * DDIM / 8) / 256, 256, 0, stream>>>(Ws, We, wc);
    k_combine_b<<<NEXP * HDIM / 256, 256, 0, stream>>>(bs, be, bc);
    k_hist<<<N_TOK / 256, 256, 0, stream>>>(eid, cnt);
    k_scan<<<1, 64, 0, stream>>>(cnt, texp, pb);
    k_scatter<<<N_TOK / 256, 256, 0, stream>>>(eid, pb, cur, perm);

    // V0: the real kernel (writes out)
    k_gemm_t<0, 1><<<256, 512, 0, stream>>>(xb, wc, bc, perm, texp, pb, out);
    // V1 diagnostic: no-VMEM skeleton, 3 sweeps, never writes out
    k_gemm_t<1, 3><<<256, 512, 0, stream>>>(xb, wc, bc, perm, texp, pb, out);
}

// Round 9
// 378.884 us; speedup vs baseline: 1.5963x; 1.5963x over previous
//
#include <hip/hip_runtime.h>
#include <stdint.h>

#define N_TOK 16384
#define DDIM  1024
#define HDIM  4096
#define NEXP  8
#define BM    256
#define MAXMT 72
#define MAXNR 5

typedef __attribute__((ext_vector_type(8))) short short8;
typedef __attribute__((ext_vector_type(4))) float f32x4;

__device__ __forceinline__ unsigned short f2b(float f) {
    union { float f; unsigned int u; } x; x.f = f;
    unsigned int r = x.u + 0x7FFFu + ((x.u >> 16) & 1u);
    return (unsigned short)(r >> 16);
}

// K1: router (fp64 accumulate => argmax matches numpy) + x -> bf16 cast.
__global__ __launch_bounds__(256)
void k_router_cast(const float* __restrict__ x, const float* __restrict__ Wr,
                   const float* __restrict__ br, unsigned short* __restrict__ xb,
                   int* __restrict__ eid)
{
    __shared__ float wr[NEXP * DDIM];
    const int t = threadIdx.x;
    for (int i = t; i < NEXP * DDIM / 4; i += 256)
        ((float4*)wr)[i] = ((const float4*)Wr)[i];
    __syncthreads();
    const int lane = t & 63;
    const int n = blockIdx.x * 4 + (t >> 6);
    const float* xr = x + (size_t)n * DDIM;
    double acc[NEXP];
#pragma unroll
    for (int e = 0; e < NEXP; ++e) acc[e] = 0.0;
#pragma unroll
    for (int j = 0; j < 4; ++j) {
        const int d = j * 256 + lane * 4;
        float4 v = *(const float4*)(xr + d);
        unsigned long long pk =
            (unsigned long long)(f2b(v.x) | ((unsigned int)f2b(v.y) << 16)) |
            ((unsigned long long)(f2b(v.z) | ((unsigned int)f2b(v.w) << 16)) << 32);
        *(unsigned long long*)(xb + (size_t)n * DDIM + d) = pk;
#pragma unroll
        for (int e = 0; e < NEXP; ++e) {
            const float* w = wr + e * DDIM + d;
            acc[e] += (double)v.x * (double)w[0];
            acc[e] += (double)v.y * (double)w[1];
            acc[e] += (double)v.z * (double)w[2];
            acc[e] += (double)v.w * (double)w[3];
        }
    }
#pragma unroll
    for (int e = 0; e < NEXP; ++e)
#pragma unroll
        for (int off = 32; off > 0; off >>= 1)
            acc[e] += __shfl_down(acc[e], off);
    if (lane == 0) {
        double best = acc[0] + (double)br[0];
        int bi = 0;
#pragma unroll
        for (int e = 1; e < NEXP; ++e) {
            double v = acc[e] + (double)br[e];
            if (v > best) { best = v; bi = e; }
        }
        eid[n] = bi;
    }
}

// K2: histogram — LDS counts then <=8 padded (64B-stride) global atomics/block.
__global__ __launch_bounds__(256)
void k_hist(const int* __restrict__ eid, int* __restrict__ counts)
{
    __shared__ int h[NEXP];
    const int t = threadIdx.x;
    if (t < NEXP) h[t] = 0;
    __syncthreads();
    atomicAdd(&h[eid[blockIdx.x * 256 + t]], 1);
    __syncthreads();
    if (t < NEXP && h[t]) atomicAdd(&counts[t * 16], h[t]);
}

// K3: tile table + realM
__global__ void k_scan(const int* __restrict__ counts, int* __restrict__ texp,
                       int* __restrict__ pbase)
{
    if (threadIdx.x == 0) {
        int tt = 0;
        for (int e = 0; e < NEXP; ++e) {
            pbase[e] = tt * BM;
            const int nt = (counts[e * 16] + BM - 1) / BM;
            for (int i = 0; i < nt; ++i) texp[tt++] = e;
        }
        pbase[8] = tt;                       // realM (<= 71)
        for (; tt < MAXMT; ++tt) texp[tt] = -1;
    }
}

// K4: scatter — LDS rank + one padded global atomic per (block, expert).
__global__ __launch_bounds__(256)
void k_scatter(const int* __restrict__ eid, const int* __restrict__ pbase,
               int* __restrict__ cursors, int* __restrict__ perm)
{
    __shared__ int h[NEXP];
    __shared__ int base[NEXP];
    const int t = threadIdx.x;
    if (t < NEXP) h[t] = 0;
    __syncthreads();
    const int n = blockIdx.x * 256 + t;
    const int e = eid[n];
    const int rank = atomicAdd(&h[e], 1);
    __syncthreads();
    if (t < NEXP) base[t] = h[t] ? atomicAdd(&cursors[t * 16], h[t]) : 0;
    __syncthreads();
    perm[pbase[e] + base[e] + rank] = n;
}

// K5a: W_comb[e] = bf16(Ws + We[e])
__global__ __launch_bounds__(256)
void k_combine_w(const float* __restrict__ Ws, const float* __restrict__ We,
                 unsigned short* __restrict__ wc)
{
    const size_t i = ((size_t)blockIdx.x * 256 + threadIdx.x) * 8;
    const size_t hd = i & (size_t)(HDIM * DDIM - 1);
    float4 a0 = *(const float4*)(We + i);
    float4 a1 = *(const float4*)(We + i + 4);
    float4 b0 = *(const float4*)(Ws + hd);
    float4 b1 = *(const float4*)(Ws + hd + 4);
    uint4 o;
    o.x = f2b(a0.x + b0.x) | ((unsigned)f2b(a0.y + b0.y) << 16);
    o.y = f2b(a0.z + b0.z) | ((unsigned)f2b(a0.w + b0.w) << 16);
    o.z = f2b(a1.x + b1.x) | ((unsigned)f2b(a1.y + b1.y) << 16);
    o.w = f2b(a1.z + b1.z) | ((unsigned)f2b(a1.w + b1.w) << 16);
    *(uint4*)(wc + i) = o;
}

// K5b: b_comb[e] = bs + be[e]
__global__ __launch_bounds__(256)
void k_combine_b(const float* __restrict__ bs, const float* __restrict__ be,
                 float* __restrict__ bc)
{
    const int i = blockIdx.x * 256 + threadIdx.x;
    bc[i] = bs[i & (HDIM - 1)] + be[i];
}

// K6: PERSISTENT gathered GEMM. BK=32, 4-slot LDS ring (4 x 32KB bytes:
// slot = A[4 planes x 256 rows x 16B] | B[same] ), ONE barrier per K-tile,
// counted vmcnt(8) (2 tiles of stages in flight), counted lgkmcnt inside
// the tile. Waves drift within a tile so one wave's ds_reads overlap the
// other wave's MFMAs on each SIMD. k-major chunk layout: conflict-free
// reads without XOR swizzle; one token per staging thread.
#define SBAR()   __builtin_amdgcn_s_barrier()
#define SCHED0() __builtin_amdgcn_sched_barrier(0)

__global__ __launch_bounds__(512, 2)
void k_gemm(const unsigned short* __restrict__ X, const unsigned short* __restrict__ W,
            const float* __restrict__ bc, const int* __restrict__ perm,
            const int* __restrict__ texp, const int* __restrict__ realM_p,
            float* __restrict__ out)
{
    __shared__ unsigned short lds[65536];       // 131072 B = 4 slots x 32768 B
    __shared__ int   toksLDS[MAXNR][256];       // epilogue scatter targets
    __shared__ float biasLDS[MAXNR][256];       // per-wg bias row (block's 256 cols)

    const int realM = realM_p[8];
    const int base  = blockIdx.x;
    const int tnr   = base & 15;
    const int tmB   = base >> 4;
    const int nR    = (realM - tmB + 15) >> 4;  // 4..5
    const int T     = nR << 5;                  // 32 K-tiles per wg

    const int t    = threadIdx.x;
    const int lane = t & 63;
    const int wid  = t >> 6;
    const int wm   = wid >> 2;
    const int wn   = wid & 3;

    const int rA   = lane & 15;
    // frag read base within a slot (BYTES): kc=(lane>>4) plane + row chunk
    const int rBase = ((lane >> 4) << 12) + (rA << 4);
    const int aOffW = (wm << 11);               // wm*128 rows * 16B
    const int colBase = tnr * 256 + wn * 64 + rA;

    // staging geometry: thread t handles row/col (t&255), k-chunk pair kcHi/kcHi+2
    const int srcRow = t & 255;
    const int kcHi   = t >> 8;                  // 0..1
    unsigned short* dstT = lds + (t << 3);      // t*16 bytes

    // ---- upfront metadata (ordinary loads; ring not yet started) ----
    int ePk = 0;
#pragma unroll
    for (int w = 0; w < MAXNR; ++w) {
        const int ev = (w < nR) ? texp[tmB + (w << 4)] : 0;
        ePk |= (ev & 15) << (w << 2);
    }
    if (t < 256) {
#pragma unroll
        for (int w = 0; w < MAXNR; ++w) {
            if (w < nR) {
                toksLDS[w][t] = perm[(tmB + (w << 4)) * 256 + t];
                const int ev = (ePk >> (w << 2)) & 15;
                biasLDS[w][t] = bc[ev * HDIM + tnr * 256 + t];
            }
        }
    }
    __syncthreads();

    int tokC, tokN;
    {
        int a = toksLDS[0][srcRow];  tokC = a < 0 ? 0 : a;
        int b = (nR > 1) ? toksLDS[1][srcRow] : 0;  tokN = b < 0 ? 0 : b;
    }

    f32x4 acc[8][4];
    {
        float bn[4];
#pragma unroll
        for (int n = 0; n < 4; ++n) bn[n] = biasLDS[0][wn * 64 + n * 16 + rA];
#pragma unroll
        for (int m = 0; m < 8; ++m)
#pragma unroll
            for (int n = 0; n < 4; ++n)
                acc[m][n] = (f32x4){bn[n], bn[n], bn[n], bn[n]};
    }
    short8 fa[8], fb[4];

    // stage K-tile st (4 x global_load_lds); tau = current tile (wg select)
    auto STAGE = [&](int st, int tau) {
        if (st >= T) return;
        const int kb   = (st & 31) << 5;             // k element base
        const int stW  = st >> 5;
        // slot base: (st&3) * 32768 BYTES = (st&3) * 16384 shorts
        unsigned short* d = dstT + ((st & 3) << 14);
        // A: gathered token row
        const int tok = (stW == (tau >> 5)) ? tokC : tokN;
        const unsigned short* sA = X + (size_t)tok * DDIM + kb + (kcHi << 3);
        // B: weight row (col = srcRow) of staged wg's expert
        const int ee = (ePk >> (stW << 2)) & 15;
        const unsigned short* sB =
            W + ((size_t)ee * HDIM + (size_t)tnr * 256 + srcRow) * DDIM + kb + (kcHi << 3);
        // LDS byte offsets: +0 (A planes kcHi), +8192 (A kcHi+2),
        //                   +16384 (B kcHi), +24576 (B kcHi+2)
        __builtin_amdgcn_global_load_lds(
            (const __attribute__((address_space(1))) void*)sA,
            (__attribute__((address_space(3))) void*)d, 16, 0, 0);
        __builtin_amdgcn_global_load_lds(
            (const __attribute__((address_space(1))) void*)(sA + 16),
            (__attribute__((address_space(3))) void*)(d + 4096), 16, 0, 0);
        __builtin_amdgcn_global_load_lds(
            (const __attribute__((address_space(1))) void*)sB,
            (__attribute__((address_space(3))) void*)(d + 8192), 16, 0, 0);
        __builtin_amdgcn_global_load_lds(
            (const __attribute__((address_space(1))) void*)(sB + 16),
            (__attribute__((address_space(3))) void*)(d + 12288), 16, 0, 0);
    };

#define LDA(m) fa[m] = *(const short8*)((const char*)lds + slotB + rBase + aOffW + ((m) << 8));
#define LDB(n) fb[n] = *(const short8*)((const char*)lds + slotB + 16384 + rBase + (wn << 10) + ((n) << 8));
#define MM(m,n) acc[m][n] = __builtin_amdgcn_mfma_f32_16x16x32_bf16(fa[m], fb[n], acc[m][n], 0,0,0);

    // prologue: stage tiles 0,1,2 (12 loads); tile0 landed, tiles1-2 in flight
    STAGE(0, 0); STAGE(1, 0); STAGE(2, 0);
    asm volatile("s_waitcnt vmcnt(8)" ::: "memory");
    SCHED0(); SBAR(); SCHED0();

    int w = 0;
#pragma unroll 1
    for (int tau = 0; tau < T; ++tau) {
        const int tt = tau & 31;
        const int slotB = (tau & 3) << 15;      // slot base in BYTES

        // stage tile tau+3 into slot (tau+3)&3 == (tau-1)&3 — safe: barrier
        // at the tau-1/tau boundary means every wave finished reading it
        STAGE(tau + 3, tau);
        SCHED0();
        // fragment reads, FIFO groups: [B0-3,A0-1] [A2-4] [A5-7]
        LDB(0) LDB(1) LDB(2) LDB(3) LDA(0) LDA(1)
        SCHED0();
        LDA(2) LDA(3) LDA(4)
        SCHED0();
        LDA(5) LDA(6) LDA(7)
        SCHED0();
        asm volatile("s_waitcnt lgkmcnt(6)" ::: "memory"); SCHED0();
        __builtin_amdgcn_s_setprio(1);
        MM(0,0) MM(0,1) MM(0,2) MM(0,3) MM(1,0) MM(1,1) MM(1,2) MM(1,3)
        __builtin_amdgcn_s_setprio(0); SCHED0();
        asm volatile("s_waitcnt lgkmcnt(3)" ::: "memory"); SCHED0();
        __builtin_amdgcn_s_setprio(1);
        MM(2,0) MM(2,1) MM(2,2) MM(2,3) MM(3,0) MM(3,1) MM(3,2) MM(3,3)
        MM(4,0) MM(4,1) MM(4,2) MM(4,3)
        __builtin_amdgcn_s_setprio(0); SCHED0();
        asm volatile("s_waitcnt lgkmcnt(0)" ::: "memory"); SCHED0();
        __builtin_amdgcn_s_setprio(1);
        MM(5,0) MM(5,1) MM(5,2) MM(5,3) MM(6,0) MM(6,1) MM(6,2) MM(6,3)
        MM(7,0) MM(7,1) MM(7,2) MM(7,3)
        __builtin_amdgcn_s_setprio(0); SCHED0();
        // single boundary: tile tau+1 fully landed; 2 tiles of stages in flight
        if (tau < T - 3)       { asm volatile("s_waitcnt vmcnt(8)" ::: "memory"); }
        else if (tau == T - 3) { asm volatile("s_waitcnt vmcnt(4)" ::: "memory"); }
        else if (tau == T - 2) { asm volatile("s_waitcnt vmcnt(0)" ::: "memory"); }
        SBAR(); SCHED0();

        if (tt == 31) {
            // ---- epilogue for wg w: pure guarded scatter-store ----
            const int rsub = (lane >> 4) * 4;
#pragma unroll
            for (int m = 0; m < 8; ++m) {
                const int rl = wm * 128 + m * 16 + rsub;
                int tk[4];
#pragma unroll
                for (int j = 0; j < 4; ++j) tk[j] = toksLDS[w][rl + j];
#pragma unroll
                for (int n = 0; n < 4; ++n) {
                    const int col = colBase + n * 16;
#pragma unroll
                    for (int j = 0; j < 4; ++j)
                        if (tk[j] >= 0) out[(size_t)tk[j] * HDIM + col] = acc[m][n][j];
                }
            }
            if (w + 1 < nR) {
                float bn[4];
#pragma unroll
                for (int n = 0; n < 4; ++n) bn[n] = biasLDS[w + 1][wn * 64 + n * 16 + rA];
#pragma unroll
                for (int m = 0; m < 8; ++m)
#pragma unroll
                    for (int n = 0; n < 4; ++n)
                        acc[m][n] = (f32x4){bn[n], bn[n], bn[n], bn[n]};
                tokC = tokN;
                if (w + 2 < nR) {
                    int v = toksLDS[w + 2][srcRow];
                    tokN = v < 0 ? 0 : v;
                }
            }
            ++w;
        }
    }
#undef LDA
#undef LDB
#undef MM
}

extern "C" void kernel_launch(void* const* d_in, const int* in_sizes, int n_in,
                              void* d_out, int out_size, void* d_ws, size_t ws_size,
                              hipStream_t stream)
{
    const float* x  = (const float*)d_in[0];
    const float* Ws = (const float*)d_in[1];
    const float* bs = (const float*)d_in[2];
    const float* We = (const float*)d_in[3];
    const float* be = (const float*)d_in[4];
    const float* Wr = (const float*)d_in[5];
    const float* br = (const float*)d_in[6];
    float* out = (float*)d_out;
    char* ws = (char*)d_ws;

    // workspace layout (~100.94 MB)
    unsigned short* xb  = (unsigned short*)(ws + 0);          // 33,554,432 B
    unsigned short* wc  = (unsigned short*)(ws + 33554432);   // 67,108,864 B
    float*          bc  = (float*)(ws + 100663296);           //    131,072 B
    int*            eid = (int*)(ws + 100794368);             //     65,536 B
    int*            perm= (int*)(ws + 100859904);             //     73,728 B
    int*            cnt = (int*)(ws + 100933632);             // 512 B (padded)
    int*            cur = (int*)(ws + 100934144);             // 512 B (padded)
    int*            pb  = (int*)(ws + 100934656);             // 64 B (pbase + realM@[8])
    int*            texp= (int*)(ws + 100934720);             // 288 B

    hipMemsetAsync(perm, 0xFF, MAXMT * BM * sizeof(int), stream);
    hipMemsetAsync(cnt, 0, 1024, stream);   // cnt + cur

    k_router_cast<<<N_TOK / 4, 256, 0, stream>>>(x, Wr, br, xb, eid);
    k_combine_w<<<(NEXP * (size_t)HDIM * DDIM / 8) / 256, 256, 0, stream>>>(Ws, We, wc);
    k_combine_b<<<NEXP * HDIM / 256, 256, 0, stream>>>(bs, be, bc);
    k_hist<<<N_TOK / 256, 256, 0, stream>>>(eid, cnt);
    k_scan<<<1, 64, 0, stream>>>(cnt, texp, pb);
    k_scatter<<<N_TOK / 256, 256, 0, stream>>>(eid, pb, cur, perm);
    k_gemm<<<256, 512, 0, stream>>>(xb, wc, bc, perm, texp, pb, out);
}

// Round 10
// 270.888 us; speedup vs baseline: 2.2328x; 1.3987x over previous
//
#include <hip/hip_runtime.h>
#include <stdint.h>

#define N_TOK 16384
#define DDIM  1024
#define HDIM  4096
#define NEXP  8
#define BM    256
#define MAXMT 72
#define MAXNR 5

#define GRID_R 4096     // router blocks (4 tokens each)
#define GRID_W 16384    // combine_w blocks
#define GRID_B 128      // combine_b blocks

typedef __attribute__((ext_vector_type(8))) short short8;
typedef __attribute__((ext_vector_type(4))) float f32x4;

__device__ __forceinline__ unsigned short f2b(float f) {
    union { float f; unsigned int u; } x; x.f = f;
    unsigned int r = x.u + 0x7FFFu + ((x.u >> 16) & 1u);
    return (unsigned short)(r >> 16);
}

// K1: FUSED prep — three independent jobs in one launch (stream would
// otherwise serialize them): router(+bf16 cast) / combine_w / combine_b.
__global__ __launch_bounds__(256)
void k_fused(const float* __restrict__ x, const float* __restrict__ Wr,
             const float* __restrict__ br, unsigned short* __restrict__ xb,
             int* __restrict__ eid,
             const float* __restrict__ Ws, const float* __restrict__ We,
             unsigned short* __restrict__ wc,
             const float* __restrict__ bs, const float* __restrict__ be,
             float* __restrict__ bc)
{
    const int bid = blockIdx.x;
    const int t = threadIdx.x;

    if (bid < GRID_R) {
        // ---- router: fp64 accumulate => argmax matches numpy; + x->bf16 ----
        __shared__ float wr[NEXP * DDIM];
        for (int i = t; i < NEXP * DDIM / 4; i += 256)
            ((float4*)wr)[i] = ((const float4*)Wr)[i];
        __syncthreads();
        const int lane = t & 63;
        const int n = bid * 4 + (t >> 6);
        const float* xr = x + (size_t)n * DDIM;
        double acc[NEXP];
#pragma unroll
        for (int e = 0; e < NEXP; ++e) acc[e] = 0.0;
#pragma unroll
        for (int j = 0; j < 4; ++j) {
            const int d = j * 256 + lane * 4;
            float4 v = *(const float4*)(xr + d);
            unsigned long long pk =
                (unsigned long long)(f2b(v.x) | ((unsigned int)f2b(v.y) << 16)) |
                ((unsigned long long)(f2b(v.z) | ((unsigned int)f2b(v.w) << 16)) << 32);
            *(unsigned long long*)(xb + (size_t)n * DDIM + d) = pk;
#pragma unroll
            for (int e = 0; e < NEXP; ++e) {
                const float* w = wr + e * DDIM + d;
                acc[e] += (double)v.x * (double)w[0];
                acc[e] += (double)v.y * (double)w[1];
                acc[e] += (double)v.z * (double)w[2];
                acc[e] += (double)v.w * (double)w[3];
            }
        }
#pragma unroll
        for (int e = 0; e < NEXP; ++e)
#pragma unroll
            for (int off = 32; off > 0; off >>= 1)
                acc[e] += __shfl_down(acc[e], off);
        if (lane == 0) {
            double best = acc[0] + (double)br[0];
            int bi = 0;
#pragma unroll
            for (int e = 1; e < NEXP; ++e) {
                double v = acc[e] + (double)br[e];
                if (v > best) { best = v; bi = e; }
            }
            eid[n] = bi;
        }
    } else if (bid < GRID_R + GRID_W) {
        // ---- combine_w: wc = bf16(Ws + We[e]) ----
        const size_t i = ((size_t)(bid - GRID_R) * 256 + t) * 8;
        const size_t hd = i & (size_t)(HDIM * DDIM - 1);
        float4 a0 = *(const float4*)(We + i);
        float4 a1 = *(const float4*)(We + i + 4);
        float4 b0 = *(const float4*)(Ws + hd);
        float4 b1 = *(const float4*)(Ws + hd + 4);
        uint4 o;
        o.x = f2b(a0.x + b0.x) | ((unsigned)f2b(a0.y + b0.y) << 16);
        o.y = f2b(a0.z + b0.z) | ((unsigned)f2b(a0.w + b0.w) << 16);
        o.z = f2b(a1.x + b1.x) | ((unsigned)f2b(a1.y + b1.y) << 16);
        o.w = f2b(a1.z + b1.z) | ((unsigned)f2b(a1.w + b1.w) << 16);
        *(uint4*)(wc + i) = o;
    } else {
        // ---- combine_b: bc = bs + be[e] ----
        const int i = (bid - GRID_R - GRID_W) * 256 + t;
        bc[i] = bs[i & (HDIM - 1)] + be[i];
    }
}

// K2: histogram — LDS counts then <=8 padded (64B-stride) global atomics/block.
__global__ __launch_bounds__(256)
void k_hist(const int* __restrict__ eid, int* __restrict__ counts)
{
    __shared__ int h[NEXP];
    const int t = threadIdx.x;
    if (t < NEXP) h[t] = 0;
    __syncthreads();
    atomicAdd(&h[eid[blockIdx.x * 256 + t]], 1);
    __syncthreads();
    if (t < NEXP && h[t]) atomicAdd(&counts[t * 16], h[t]);
}

// K3: scatter — pbase derived inline from counts (k_scan removed);
// LDS rank + one padded global atomic per (block, expert).
__global__ __launch_bounds__(256)
void k_scatter(const int* __restrict__ eid, const int* __restrict__ counts,
               int* __restrict__ cursors, int* __restrict__ perm)
{
    __shared__ int cl[NEXP];
    __shared__ int h[NEXP];
    __shared__ int base[NEXP];
    const int t = threadIdx.x;
    if (t < NEXP) { cl[t] = counts[t * 16]; h[t] = 0; }
    __syncthreads();
    const int n = blockIdx.x * 256 + t;
    const int e = eid[n];
    // pbase[e] = 256 * (sum of tile counts of experts < e)
    int p = 0;
#pragma unroll
    for (int ee = 0; ee < NEXP; ++ee)
        if (ee < e) p += (cl[ee] + 255) >> 8;
    const int pbase = p << 8;
    const int rank = atomicAdd(&h[e], 1);
    __syncthreads();
    if (t < NEXP) base[t] = h[t] ? atomicAdd(&cursors[t * 16], h[t]) : 0;
    __syncthreads();
    perm[pbase + base[e] + rank] = n;
}

// K4: PERSISTENT gathered GEMM — exact round-6 core (best measured: 190us).
// grid=256 (1 block/CU), block b: tn=b&15 fixed, sweeps tm=(b>>4)+16w, w<nR.
// Tile-top fragment reads in FIFO groups gated by counted lgkmcnt; mid
// barrier + boundary counted vmcnt(6); T2 XOR swizzle; setprio on MFMA.
// Metadata (texp/realM) derived inline from counts — k_scan removed.
#define SBAR()   __builtin_amdgcn_s_barrier()
#define SCHED0() __builtin_amdgcn_sched_barrier(0)
#define LGKM0()  asm volatile("s_waitcnt lgkmcnt(0)" ::: "memory")

__global__ __launch_bounds__(512, 2)
void k_gemm(const unsigned short* __restrict__ X, const unsigned short* __restrict__ W,
            const float* __restrict__ bc, const int* __restrict__ perm,
            const int* __restrict__ cnt, float* __restrict__ out)
{
    __shared__ unsigned short lds[65536];       // 128 KiB ring
    __shared__ int   toksLDS[MAXNR][256];       // epilogue scatter targets
    __shared__ float biasLDS[MAXNR][256];       // per-wg bias row (block's 256 cols)

    const int base  = blockIdx.x;
    const int tnr   = base & 15;
    const int tmB   = base >> 4;

    // inline tile table: nt[e] = ceil(counts[e]/256); realM = sum
    int ntE[NEXP]; int realM = 0;
#pragma unroll
    for (int e = 0; e < NEXP; ++e) {
        ntE[e] = (cnt[e * 16] + 255) >> 8;
        realM += ntE[e];
    }
    const int nR = (realM - tmB + 15) >> 4;     // 4..5
    const int T  = nR << 4;

    const int t    = threadIdx.x;
    const int lane = t & 63;
    const int wid  = t >> 6;
    const int wm   = wid >> 2;
    const int wn   = wid & 3;

    const int srow    = t >> 3;                        // 0..63
    const int schunkE = (((t & 7) ^ (srow & 7)) << 3); // swizzled src k-offset
    unsigned short* dstT = lds + (t << 3);

    const int rA   = lane & 15;
    const int c0   = ((lane >> 4) << 3) ^ ((lane & 7) << 3);
    const int c1   = c0 ^ 32;
    const int aBase = ((2 + wm) << 13) + (rA << 6);
    const int bBase = ((wn >> 1) << 13) + ((wn & 1) << 12) + (rA << 6);
    const int colBase = tnr * 256 + wn * 64 + rA;

    // ePk: expert of wg w = largest e with prefix[e] <= tmB + 16w
    int ePk = 0;
#pragma unroll
    for (int w = 0; w < MAXNR; ++w) {
        int ev = 0;
        if (w < nR) {
            const int tmW = tmB + (w << 4);
            int pre = 0;
#pragma unroll
            for (int e = 0; e < NEXP; ++e) {
                if (tmW >= pre) ev = e;
                pre += ntE[e];
            }
        }
        ePk |= (ev & 15) << (w << 2);
    }
    if (t < 256) {
#pragma unroll
        for (int w = 0; w < MAXNR; ++w) {
            if (w < nR) {
                toksLDS[w][t] = perm[(tmB + (w << 4)) * 256 + t];
                const int ev = (ePk >> (w << 2)) & 15;
                biasLDS[w][t] = bc[ev * HDIM + tnr * 256 + t];
            }
        }
    }
    __syncthreads();

    int tokCur[4], tokNext[4];
#pragma unroll
    for (int i = 0; i < 4; ++i) {
        int a = toksLDS[0][i * 64 + srow];
        tokCur[i] = a < 0 ? 0 : a;
        int b = (nR > 1) ? toksLDS[1][i * 64 + srow] : 0;
        tokNext[i] = b < 0 ? 0 : b;
    }

    f32x4 acc[8][4];
    {
        float bn[4];
#pragma unroll
        for (int n = 0; n < 4; ++n) bn[n] = biasLDS[0][wn * 64 + n * 16 + rA];
#pragma unroll
        for (int m = 0; m < 8; ++m)
#pragma unroll
            for (int n = 0; n < 4; ++n)
                acc[m][n] = (f32x4){bn[n], bn[n], bn[n], bn[n]};
    }
    short8 fa[8][2], fb[4][2];

    auto STAGE = [&](int sg, int tau) {
        if (sg >= (nR << 6)) return;
        const int tloc = sg >> 2;
        const int h    = sg & 3;
        const int kb   = (tloc & 15) << 6;
        unsigned short* d = dstT + ((tloc & 1) << 15) + (h << 13);
        const unsigned short *s0, *s1;
        if (h < 2) {
            const int wS = tloc >> 4;
            const int ee = (ePk >> (wS << 2)) & 15;
            const size_t r0 = (size_t)(ee * HDIM + tnr * 256 + h * 128 + srow) * DDIM
                              + schunkE + kb;
            s0 = W + r0; s1 = W + r0 + (size_t)64 * DDIM;
        } else {
            const bool nxt = (tloc >> 4) != (tau >> 4);
            const int i0 = (h - 2) << 1;
            const int ta = nxt ? tokNext[i0]     : tokCur[i0];
            const int tb = nxt ? tokNext[i0 + 1] : tokCur[i0 + 1];
            s0 = X + (size_t)ta * DDIM + schunkE + kb;
            s1 = X + (size_t)tb * DDIM + schunkE + kb;
        }
        __builtin_amdgcn_global_load_lds(
            (const __attribute__((address_space(1))) void*)s0,
            (__attribute__((address_space(3))) void*)d, 16, 0, 0);
        __builtin_amdgcn_global_load_lds(
            (const __attribute__((address_space(1))) void*)s1,
            (__attribute__((address_space(3))) void*)(d + 4096), 16, 0, 0);
    };

#define LDA(m) \
    fa[m][0] = *(const short8*)&lds[bufOff + aBase + (m)*1024 + c0]; \
    fa[m][1] = *(const short8*)&lds[bufOff + aBase + (m)*1024 + c1];
#define LDB(n) \
    fb[n][0] = *(const short8*)&lds[bufOff + bBase + (n)*1024 + c0]; \
    fb[n][1] = *(const short8*)&lds[bufOff + bBase + (n)*1024 + c1];
#define MM(m,n) \
    acc[m][n] = __builtin_amdgcn_mfma_f32_16x16x32_bf16(fa[m][0], fb[n][0], acc[m][n], 0,0,0); \
    acc[m][n] = __builtin_amdgcn_mfma_f32_16x16x32_bf16(fa[m][1], fb[n][1], acc[m][n], 0,0,0);

    // ring prologue: tile0 fully landed; 3 half-tiles (6 loads) stay in flight
#pragma unroll
    for (int s = 0; s < 7; ++s) STAGE(s, 0);
    asm volatile("s_waitcnt vmcnt(6)" ::: "memory");
    SCHED0(); SBAR(); SCHED0();

    int w = 0;
#pragma unroll 1
    for (int tau = 0; tau < T; ++tau) {
        const int tt = tau & 15;
        const int bufOff = (tau & 1) << 15;
        const int sig = (tau << 2) + 7;

        // ---- tile top: all fragment reads, FIFO-grouped ----
        LDB(0) LDB(1) LDB(2) LDB(3) LDA(0) LDA(1)    // G1: 12 reads
        SCHED0();
        LDA(2) LDA(3)                                // G2: 4 reads
        SCHED0();
        LDA(4) LDA(5) LDA(6) LDA(7)                  // G3: 8 reads
        STAGE(sig, tau);                             // other-buffer H3: always safe
        SCHED0();
        asm volatile("s_waitcnt lgkmcnt(12)" ::: "memory"); SCHED0();
        __builtin_amdgcn_s_setprio(1);
        MM(0,0) MM(0,1) MM(0,2) MM(0,3) MM(1,0) MM(1,1) MM(1,2) MM(1,3)
        __builtin_amdgcn_s_setprio(0); SCHED0();
        asm volatile("s_waitcnt lgkmcnt(8)" ::: "memory"); SCHED0();
        __builtin_amdgcn_s_setprio(1);
        MM(2,0) MM(2,1) MM(2,2) MM(2,3) MM(3,0) MM(3,1) MM(3,2) MM(3,3)
        __builtin_amdgcn_s_setprio(0); SCHED0();
        // ---- mid barrier: all waves' reads complete -> safe to overwrite-stage
        LGKM0(); SBAR(); SCHED0();
        STAGE(sig + 1, tau); STAGE(sig + 2, tau); STAGE(sig + 3, tau);
        SCHED0();
        __builtin_amdgcn_s_setprio(1);
        MM(4,0) MM(4,1) MM(4,2) MM(4,3) MM(5,0) MM(5,1) MM(5,2) MM(5,3)
        MM(6,0) MM(6,1) MM(6,2) MM(6,3) MM(7,0) MM(7,1) MM(7,2) MM(7,3)
        __builtin_amdgcn_s_setprio(0); SCHED0();
        // ---- boundary: tile tau+1 fully landed, 3 stages in flight ----
        if (tau < T - 2)       { asm volatile("s_waitcnt vmcnt(6)" ::: "memory"); }
        else if (tau == T - 2) { asm volatile("s_waitcnt vmcnt(0)" ::: "memory"); }
        SBAR(); SCHED0();

        if (tt == 15) {
            // ---- epilogue for wg w: pure guarded scatter-store ----
            const int rsub = (lane >> 4) * 4;
#pragma unroll
            for (int m = 0; m < 8; ++m) {
                const int rl = wm * 128 + m * 16 + rsub;
                int tk[4];
#pragma unroll
                for (int j = 0; j < 4; ++j) tk[j] = toksLDS[w][rl + j];
#pragma unroll
                for (int n = 0; n < 4; ++n) {
                    const int col = colBase + n * 16;
#pragma unroll
                    for (int j = 0; j < 4; ++j)
                        if (tk[j] >= 0) out[(size_t)tk[j] * HDIM + col] = acc[m][n][j];
                }
            }
            if (w + 1 < nR) {
                float bn[4];
#pragma unroll
                for (int n = 0; n < 4; ++n) bn[n] = biasLDS[w + 1][wn * 64 + n * 16 + rA];
#pragma unroll
                for (int m = 0; m < 8; ++m)
#pragma unroll
                    for (int n = 0; n < 4; ++n)
                        acc[m][n] = (f32x4){bn[n], bn[n], bn[n], bn[n]};
#pragma unroll
                for (int i = 0; i < 4; ++i) tokCur[i] = tokNext[i];
                if (w + 2 < nR) {
#pragma unroll
                    for (int i = 0; i < 4; ++i) {
                        int v = toksLDS[w + 2][i * 64 + srow];
                        tokNext[i] = v < 0 ? 0 : v;
                    }
                }
            }
            ++w;
        }
    }
#undef LDA
#undef LDB
#undef MM
}

extern "C" void kernel_launch(void* const* d_in, const int* in_sizes, int n_in,
                              void* d_out, int out_size, void* d_ws, size_t ws_size,
                              hipStream_t stream)
{
    const float* x  = (const float*)d_in[0];
    const float* Ws = (const float*)d_in[1];
    const float* bs = (const float*)d_in[2];
    const float* We = (const float*)d_in[3];
    const float* be = (const float*)d_in[4];
    const float* Wr = (const float*)d_in[5];
    const float* br = (const float*)d_in[6];
    float* out = (float*)d_out;
    char* ws = (char*)d_ws;

    // workspace layout (~100.94 MB)
    unsigned short* xb  = (unsigned short*)(ws + 0);          // 33,554,432 B
    unsigned short* wc  = (unsigned short*)(ws + 33554432);   // 67,108,864 B
    float*          bc  = (float*)(ws + 100663296);           //    131,072 B
    int*            eid = (int*)(ws + 100794368);             //     65,536 B
    int*            perm= (int*)(ws + 100859904);             //     73,728 B
    int*            cnt = (int*)(ws + 100933632);             // 512 B (padded)
    int*            cur = (int*)(ws + 100934144);             // 512 B (padded)

    hipMemsetAsync(perm, 0xFF, MAXMT * BM * sizeof(int), stream);
    hipMemsetAsync(cnt, 0, 1024, stream);   // cnt + cur

    k_fused<<<GRID_R + GRID_W + GRID_B, 256, 0, stream>>>(
        x, Wr, br, xb, eid, Ws, We, wc, bs, be, bc);
    k_hist<<<N_TOK / 256, 256, 0, stream>>>(eid, cnt);
    k_scatter<<<N_TOK / 256, 256, 0, stream>>>(eid, cnt, cur, perm);
    k_gemm<<<256, 512, 0, stream>>>(xb, wc, bc, perm, cnt, out);
}